// Round 1
// baseline (56.358 us; speedup 1.0000x reference)
//
#include <hip/hip_runtime.h>
#include <math.h>

// Problem constants (from reference)
#define BS 4
#define S 4096
#define H 32
#define KVH 8
#define HD 128
#define G 4            // H / KVH
#define WIN 1024
#define SCALE 0.08838834764831843f  // 1/sqrt(128)

// Flash-decoding split
#define NSPLIT 16
#define CHUNK (WIN / NSPLIT)   // 64 positions per block
#define PSTRIDE 130            // 128 out + m + l  (floats)

// Kernel 1: one block per (b, kvh, split). 4 waves; wave g handles head h=kvh*G+g.
// Each wave: QK over CHUNK positions (lane holds 2 dims, full-wave shuffle reduce),
// then online partial softmax + PV accumulation. Partials -> ws.
__global__ __launch_bounds__(256) void attn_split_kernel(
    const float* __restrict__ q, const float* __restrict__ k,
    const float* __restrict__ v, const float* __restrict__ mask,
    const int* __restrict__ start_positions, float* __restrict__ ws)
{
    const int blk   = blockIdx.x;
    const int split = blk % NSPLIT;
    const int kvh   = (blk / NSPLIT) % KVH;
    const int b     = blk / (NSPLIT * KVH);
    const int g     = threadIdx.x >> 6;
    const int lane  = threadIdx.x & 63;
    const int h     = kvh * G + g;

    const int p  = start_positions[b];         // last valid position
    const int lo = p - WIN + 1;                // window start (may be <0)
    const int base_pos = lo + split * CHUNK;

    __shared__ float sc[G][CHUNK];

    // q fragment for this head's last token: lane holds dims 2*lane, 2*lane+1
    const float* qptr = q + (((size_t)b * S + (S - 1)) * H + h) * HD;
    const float2 q2 = *(const float2*)(qptr + 2 * lane);

    float m = -1e30f;
    for (int jj = 0; jj < CHUNK; ++jj) {
        const int pos = base_pos + jj;
        const bool valid = (pos >= 0) && (pos <= p);   // pos<=p always true, keep for safety
        float s_val = -1e30f;
        if (valid) {
            const int row = (pos == p) ? (S - 1) : pos;  // last-token cache overwrite semantics
            const float* kptr = k + (((size_t)b * S + row) * KVH + kvh) * HD;
            const float2 k2 = *(const float2*)(kptr + 2 * lane);
            float part = q2.x * k2.x + q2.y * k2.y;
            #pragma unroll
            for (int off = 1; off < 64; off <<= 1)
                part += __shfl_xor(part, off, 64);
            s_val = part * SCALE + mask[(size_t)b * S + pos];
        }
        if (lane == 0) sc[g][jj] = s_val;
        m = fmaxf(m, s_val);
    }
    __syncthreads();

    float lsum = 0.f;
    float ox = 0.f, oy = 0.f;
    for (int jj = 0; jj < CHUNK; ++jj) {
        const int pos = base_pos + jj;
        if (pos < 0 || pos > p) continue;
        const float e = __expf(sc[g][jj] - m);
        lsum += e;
        const int row = (pos == p) ? (S - 1) : pos;
        const float* vptr = v + (((size_t)b * S + row) * KVH + kvh) * HD;
        const float2 v2 = *(const float2*)(vptr + 2 * lane);
        ox += e * v2.x;
        oy += e * v2.y;
    }

    const size_t widx = ((((size_t)b * KVH + kvh) * G + g) * NSPLIT + split) * (size_t)PSTRIDE;
    float2 o2; o2.x = ox; o2.y = oy;
    *(float2*)(ws + widx + 2 * lane) = o2;
    if (lane == 0) {
        ws[widx + 128] = m;
        ws[widx + 129] = lsum;
    }
}

// Kernel 2: one wave per (b, h). Merge NSPLIT partials + sink, write f32 output.
__global__ __launch_bounds__(64) void attn_reduce_kernel(
    const float* __restrict__ ws, const float* __restrict__ sink,
    float* __restrict__ out)
{
    const int blk = blockIdx.x;    // b*H + h
    const int h = blk % H;
    const int b = blk / H;
    const int kvh = h / G;
    const int g = h % G;
    const int lane = threadIdx.x;

    const size_t base = (((size_t)b * KVH + kvh) * G + g) * NSPLIT;

    const float sk = sink[h];
    float M = sk;
    float ms[NSPLIT];
    #pragma unroll
    for (int s = 0; s < NSPLIT; ++s) {
        ms[s] = ws[(base + s) * PSTRIDE + 128];
        M = fmaxf(M, ms[s]);
    }

    float D = __expf(sk - M);
    float ax = 0.f, ay = 0.f;
    #pragma unroll
    for (int s = 0; s < NSPLIT; ++s) {
        const float w = __expf(ms[s] - M);
        D += w * ws[(base + s) * PSTRIDE + 129];
        const float2 o2 = *(const float2*)(ws + (base + s) * PSTRIDE + 2 * lane);
        ax += w * o2.x;
        ay += w * o2.y;
    }

    const float invD = 1.f / D;
    float2 r; r.x = ax * invD; r.y = ay * invD;
    *(float2*)(out + ((size_t)b * H + h) * HD + 2 * lane) = r;
}

extern "C" void kernel_launch(void* const* d_in, const int* in_sizes, int n_in,
                              void* d_out, int out_size, void* d_ws, size_t ws_size,
                              hipStream_t stream) {
    const float* q    = (const float*)d_in[0];
    const float* k    = (const float*)d_in[1];
    const float* v    = (const float*)d_in[2];
    // d_in[3] k_cache, d_in[4] v_cache, d_in[7] seq_block_ids: not needed for the
    // output — scatter-then-gather with injective page ids is the identity, and the
    // last-token overwrite is handled by the row remap (pos==p -> S-1).
    const float* mask = (const float*)d_in[5];
    const float* sink = (const float*)d_in[6];
    const int* start_positions = (const int*)d_in[8];
    float* out = (float*)d_out;
    float* ws  = (float*)d_ws;   // needs BS*KVH*G*NSPLIT*PSTRIDE*4 B ~= 1.04 MB

    attn_split_kernel<<<BS * KVH * NSPLIT, 256, 0, stream>>>(q, k, v, mask, start_positions, ws);
    attn_reduce_kernel<<<BS * H, 64, 0, stream>>>(ws, sink, out);
}

// Round 2
// 17.823 us; speedup vs baseline: 3.1622x; 3.1622x over previous
//
#include <hip/hip_runtime.h>
#include <math.h>

// Problem constants (from reference)
#define BS 4
#define S 4096
#define H 32
#define KVH 8
#define HD 128
#define G 4            // H / KVH
#define WIN 1024
#define SCALE 0.08838834764831843f  // 1/sqrt(128)

// Flash-decoding split
#define NSPLIT 32
#define CHUNK (WIN / NSPLIT)   // 32 positions per block
#define PSTRIDE 132            // 128 out + m + l + 2 pad (keeps float4 alignment)

// Kernel 1: one block per (b, kvh, split). 4 waves; wave g handles head h=kvh*G+g.
// QK: 16-lane thread-groups, each owns 8 dims; 4 positions in flight per iteration,
// 4-shuffle group reduce. PV: half-wave per row, float4 per lane, xor-32 combine.
__global__ __launch_bounds__(256) void attn_split_kernel(
    const float* __restrict__ q, const float* __restrict__ k,
    const float* __restrict__ v, const float* __restrict__ mask,
    const int* __restrict__ start_positions, float* __restrict__ ws)
{
    const int blk   = blockIdx.x;
    const int split = blk % NSPLIT;
    const int kvh   = (blk / NSPLIT) % KVH;
    const int b     = blk / (NSPLIT * KVH);
    const int tid   = threadIdx.x;
    const int g     = tid >> 6;
    const int lane  = tid & 63;
    const int grp   = lane >> 4;   // 0..3: position group
    const int l16   = lane & 15;   // dim slot within group
    const int h     = kvh * G + g;

    const int p = start_positions[b];             // last valid position
    const int base_pos = p - WIN + 1 + split * CHUNK;

    __shared__ float sc[G][CHUNK];

    // q fragment: dims [l16*8, l16*8+8) of this head's last token
    const float* qptr = q + (((size_t)b * S + (S - 1)) * H + h) * HD + l16 * 8;
    const float4 qa = *(const float4*)(qptr);
    const float4 qb = *(const float4*)(qptr + 4);

    const size_t kv_base = (size_t)b * S * (KVH * HD) + (size_t)kvh * HD;

    // ---- QK: CHUNK/4 iterations, 4 positions (one per group) in flight ----
    #pragma unroll
    for (int it = 0; it < CHUNK / 4; ++it) {
        const int jj  = it * 4 + grp;
        const int pos = base_pos + jj;
        float val = -1e30f;
        if (pos >= 0) {                                  // pos <= p always holds
            const int row = (pos == p) ? (S - 1) : pos;  // last-token overwrite semantics
            const float* kptr = k + kv_base + (size_t)row * (KVH * HD) + l16 * 8;
            const float4 ka = *(const float4*)(kptr);
            const float4 kb = *(const float4*)(kptr + 4);
            float d = qa.x * ka.x + qa.y * ka.y + qa.z * ka.z + qa.w * ka.w
                    + qb.x * kb.x + qb.y * kb.y + qb.z * kb.z + qb.w * kb.w;
            #pragma unroll
            for (int off = 1; off < 16; off <<= 1)       // reduce within 16-lane group
                d += __shfl_xor(d, off, 64);
            val = d * SCALE + mask[(size_t)b * S + pos];
        }
        if (l16 == 0) sc[g][jj] = val;
    }

    // ---- partial softmax over this chunk (within wave; LDS RAW handled by compiler) ----
    const float s_l = sc[g][lane & (CHUNK - 1)];
    float m = s_l;
    #pragma unroll
    for (int off = 1; off < 32; off <<= 1)
        m = fmaxf(m, __shfl_xor(m, off, 64));            // max over the 32 scores
    const float e_l = __expf(s_l - m);                   // exp(-1e30 - m) -> 0 for masked
    if (lane < CHUNK) sc[g][lane] = e_l;
    float lsum = (lane < CHUNK) ? e_l : 0.f;
    #pragma unroll
    for (int off = 1; off < 64; off <<= 1)
        lsum += __shfl_xor(lsum, off, 64);

    // ---- PV: 2 rows per load instruction (half-wave each), float4 per lane ----
    const int half = lane >> 5;
    const int l32  = lane & 31;
    float4 o4 = make_float4(0.f, 0.f, 0.f, 0.f);
    #pragma unroll
    for (int it = 0; it < CHUNK / 2; ++it) {
        const int jj  = it * 2 + half;
        const int pos = base_pos + jj;
        const int row = (pos == p) ? (S - 1) : (pos < 0 ? 0 : pos);  // clamp for addr safety; e==0 kills value
        const float e = sc[g][jj];
        const float4 v4 = *(const float4*)(v + kv_base + (size_t)row * (KVH * HD) + l32 * 4);
        o4.x += e * v4.x; o4.y += e * v4.y; o4.z += e * v4.z; o4.w += e * v4.w;
    }
    o4.x += __shfl_xor(o4.x, 32, 64);
    o4.y += __shfl_xor(o4.y, 32, 64);
    o4.z += __shfl_xor(o4.z, 32, 64);
    o4.w += __shfl_xor(o4.w, 32, 64);

    const size_t widx = ((((size_t)b * KVH + kvh) * G + g) * NSPLIT + split) * (size_t)PSTRIDE;
    if (lane < 32) {
        *(float4*)(ws + widx + 4 * l32) = o4;
        if (lane == 0) { ws[widx + 128] = m; ws[widx + 129] = lsum; }
    }
}

// Kernel 2: one wave per (b, h). Merge NSPLIT partials + sink, write f32 output.
__global__ __launch_bounds__(64) void attn_reduce_kernel(
    const float* __restrict__ ws, const float* __restrict__ sink,
    float* __restrict__ out)
{
    const int blk = blockIdx.x;    // b*H + h
    const int h = blk % H;
    const int b = blk / H;
    const int kvh = h / G;
    const int g = h % G;
    const int lane = threadIdx.x;

    const size_t base = ((((size_t)b * KVH + kvh) * G + g) * (size_t)NSPLIT) * (size_t)PSTRIDE;

    const float sk = sink[h];
    float M = sk;
    float ms[NSPLIT];
    #pragma unroll
    for (int s = 0; s < NSPLIT; ++s) {
        ms[s] = ws[base + (size_t)s * PSTRIDE + 128];
        M = fmaxf(M, ms[s]);
    }

    float D = __expf(sk - M);
    float ax = 0.f, ay = 0.f;
    #pragma unroll
    for (int s = 0; s < NSPLIT; ++s) {
        const float w = __expf(ms[s] - M);
        D += w * ws[base + (size_t)s * PSTRIDE + 129];
        const float2 o2 = *(const float2*)(ws + base + (size_t)s * PSTRIDE + 2 * lane);
        ax += w * o2.x;
        ay += w * o2.y;
    }

    const float invD = 1.f / D;
    float2 r; r.x = ax * invD; r.y = ay * invD;
    *(float2*)(out + ((size_t)b * H + h) * HD + 2 * lane) = r;
}

extern "C" void kernel_launch(void* const* d_in, const int* in_sizes, int n_in,
                              void* d_out, int out_size, void* d_ws, size_t ws_size,
                              hipStream_t stream) {
    const float* q    = (const float*)d_in[0];
    const float* k    = (const float*)d_in[1];
    const float* v    = (const float*)d_in[2];
    // d_in[3] k_cache, d_in[4] v_cache, d_in[7] seq_block_ids: not needed for the
    // output — scatter-then-gather with injective page ids is the identity, and the
    // last-token overwrite is handled by the row remap (pos==p -> S-1).
    const float* mask = (const float*)d_in[5];
    const float* sink = (const float*)d_in[6];
    const int* start_positions = (const int*)d_in[8];
    float* out = (float*)d_out;
    float* ws  = (float*)d_ws;   // needs BS*KVH*G*NSPLIT*PSTRIDE*4 B ~= 2.2 MB (ws is ~1 GB)

    attn_split_kernel<<<BS * KVH * NSPLIT, 256, 0, stream>>>(q, k, v, mask, start_positions, ws);
    attn_reduce_kernel<<<BS * H, 64, 0, stream>>>(ws, sink, out);
}